// Round 6
// baseline (391.390 us; speedup 1.0000x reference)
//
#include <hip/hip_runtime.h>

#define SQ   2048
#define DIMD 2048
#define NH   16
#define HD   128
#define MR   4096   // B*S
#define QBLK 128
#define KBLK 64

using u16 = unsigned short;
using u32 = unsigned int;
using s16x8 = __attribute__((ext_vector_type(8))) short;
using u16x8 = __attribute__((ext_vector_type(8))) unsigned short;
using f32x4 = __attribute__((ext_vector_type(4))) float;
using as3u  = __attribute__((address_space(3))) u32;
using as1u  = __attribute__((address_space(1))) u32;

__device__ __forceinline__ u16 f2bf(float f) {
  u32 x = __float_as_uint(f);
  return (u16)((x + 0x7fffu + ((x >> 16) & 1u)) >> 16);
}
__device__ __forceinline__ float bf2f(u16 u) {
  return __uint_as_float(((u32)u) << 16);
}
__device__ __forceinline__ void gld16(const void* g, void* l) {
  __builtin_amdgcn_global_load_lds((as1u*)g, (as3u*)l, 16, 0, 0);
}
#define MFMA16 __builtin_amdgcn_mfma_f32_16x16x32_bf16

// ---------------- fp32 -> bf16 convert ----------------
__global__ __launch_bounds__(256) void cvt_bf16(const float* __restrict__ s,
                                                u16* __restrict__ d, int n4) {
  int i = blockIdx.x * 256 + threadIdx.x;
  int st = gridDim.x * 256;
  for (; i < n4; i += st) {
    float4 v = ((const float4*)s)[i];
    u32 lo = (u32)f2bf(v.x) | ((u32)f2bf(v.y) << 16);
    u32 hi = (u32)f2bf(v.z) | ((u32)f2bf(v.w) << 16);
    ((uint2*)d)[i] = make_uint2(lo, hi);
  }
}

// ---------------- RoPE (1 wave = 1 row of 128) ----------------
__global__ __launch_bounds__(256) void rope_kernel(
    const u16* __restrict__ Qin, const u16* __restrict__ Kin,
    u16* __restrict__ Qout, u16* __restrict__ Kout,
    const float* __restrict__ cosT, const float* __restrict__ sinT) {
  int ten = blockIdx.y;
  const u16* in = ten ? Kin : Qin;
  u16* outp     = ten ? Kout : Qout;
  float scl     = ten ? 1.0f : 0.08838834764831845f;  // fold 1/sqrt(DH) into Q
  int row = blockIdx.x * 4 + (threadIdx.x >> 6);
  int j   = threadIdx.x & 63;
  int s   = row & (SQ - 1);
  const u16* r = in + (size_t)row * HD;
  u16* w = outp + (size_t)row * HD;
  float c  = cosT[s * HD + j];
  float si = sinT[s * HD + j];
  float a  = bf2f(r[j]);
  float b  = bf2f(r[j + 64]);
  float ev = bf2f(r[2 * j]);
  float od = bf2f(r[2 * j + 1]);
  w[j]      = f2bf((a * c - od * si) * scl);
  w[j + 64] = f2bf((b * c + ev * si) * scl);
}

// ---------------- V (b,h,s,dh) -> Vt (b,h,dh,s) ----------------
__global__ __launch_bounds__(256) void transpose_v(const u16* __restrict__ V,
                                                   u16* __restrict__ Vt) {
  __shared__ u16 tile[64][72];
  int sb = blockIdx.x, db = blockIdx.y, bh = blockIdx.z;
  int r  = threadIdx.x >> 3;
  int c8 = (threadIdx.x & 7) * 8;
  const u16* src = V + ((size_t)bh * SQ + sb * 64) * HD + db * 64;
#pragma unroll
  for (int p2 = 0; p2 < 2; p2++) {
    int row = p2 * 32 + r;
    u16x8 v = *(const u16x8*)(src + (size_t)row * HD + c8);
#pragma unroll
    for (int k2 = 0; k2 < 8; k2++) tile[row][c8 + k2] = v[k2];
  }
  __syncthreads();
  u16* dst = Vt + ((size_t)bh * HD + db * 64) * SQ + sb * 64;
#pragma unroll
  for (int p2 = 0; p2 < 2; p2++) {
    int dr = p2 * 32 + r;
    u16x8 o;
#pragma unroll
    for (int k2 = 0; k2 < 8; k2++) o[k2] = tile[c8 + k2][dr];
    *(u16x8*)(dst + (size_t)dr * SQ + c8) = o;
  }
}

// ---------------- GEMM  C = A(M,K) * W(N,K)^T  (triple-buffer, 1 barrier/tile)
// BN=256 fixed, BM = 256 (MODE 0, QKV) or 128 (MODE 1, O-proj). BK=32.
// 512 thr = 8 waves (2M x 4N). Triple-buffered LDS: stage tile kt+2 while
// computing kt; ONE counted vmcnt + ONE raw barrier per K-tile, 32 (16) MFMA
// per barrier. Invariant at tile end: outstanding vm loads = tile kt+2's
// stage => tile kt+1 resident. Plain LDS loads => compiler inserts its own
// fine-grained lgkm waits (no manual pinning).
// Layout is LINEAR both sides. 64-B rows: frag-read addr mod 128 =
// 64*(r&1)+16*lg -> every bank-quad hit by 8 lanes w/ distinct addrs =
// wave-b128 floor; no swizzle needed (prior round's row-escaping XOR was
// the NaN source).
template <int MODE>
__global__ __launch_bounds__(512, 2) void gemm_tb(
    const u16* __restrict__ A, const u16* __restrict__ W,
    u16* __restrict__ Obf, float* __restrict__ Ofp) {
  constexpr int BM  = (MODE == 0) ? 256 : 128;
  constexpr int MF  = BM / 32;        // A-frags per wave (8 / 4)
  constexpr int ALD = BM / 128;       // A gld16 per thread (2 / 1)
  __shared__ alignas(16) u16 lA[3][BM * 32];
  __shared__ alignas(16) u16 lB[3][256 * 32];
  int t = threadIdx.x;
  int l = t & 63, l15 = l & 15, lg = l >> 4;
  int wid = t >> 6, wm = wid >> 2, wn = wid & 3;
  // bijective XCD swizzle
  int orig = blockIdx.x;
  constexpr int CPX = (MODE == 0) ? 48 : 32;   // 384/8, 256/8
  int li = (orig & 7) * CPX + (orig >> 3);
  constexpr int MT = (MODE == 0) ? 16 : 32;    // M tiles
  int mB = li % MT, nB = li / MT;
  int m0 = mB * BM, n0 = nB * 256;
  const u16* Ag = A + (size_t)m0 * DIMD;
  const u16* Wg = W + (size_t)n0 * DIMD;

  f32x4 acc[MF][4];
#pragma unroll
  for (int a1 = 0; a1 < MF; a1++)
#pragma unroll
    for (int b1 = 0; b1 < 4; b1++) acc[a1][b1] = (f32x4){0.f, 0.f, 0.f, 0.f};

  // staging: thread t covers LDS bytes t*16 (and +8192); LINEAR map
  int o0 = t * 16, o1 = t * 16 + 8192;
  int br0 = o0 >> 6, ac0 = (o0 & 63) >> 1;   // row, elem-col in tile
  int br1 = o1 >> 6, ac1 = (o1 & 63) >> 1;

  auto stage = [&](int buf, int kt) {
    const u16* Ws = Wg + kt * 32;
    const u16* As = Ag + kt * 32;
    gld16(Ws + (size_t)br0 * DIMD + ac0, &lB[buf][o0 >> 1]);
    gld16(Ws + (size_t)br1 * DIMD + ac1, &lB[buf][o1 >> 1]);
    gld16(As + (size_t)br0 * DIMD + ac0, &lA[buf][o0 >> 1]);
    if (ALD == 2) gld16(As + (size_t)br1 * DIMD + ac1, &lA[buf][o1 >> 1]);
  };

  // read offsets (bytes), LINEAR
  int aoff[MF], boff[4];
#pragma unroll
  for (int mf = 0; mf < MF; mf++) {
    int r = wm * (BM / 2) + mf * 16 + l15;
    aoff[mf] = r * 64 + lg * 16;
  }
#pragma unroll
  for (int nf = 0; nf < 4; nf++) {
    int r = wn * 64 + nf * 16 + l15;
    boff[nf] = r * 64 + lg * 16;
  }

  const int NKT = DIMD / 32;  // 64 K-tiles
  stage(0, 0);
  stage(1, 1);
  if constexpr (MODE == 0) asm volatile("s_waitcnt vmcnt(4)" ::: "memory");
  else                     asm volatile("s_waitcnt vmcnt(3)" ::: "memory");
  __builtin_amdgcn_s_barrier();

  int bcur = 0;
#pragma unroll 1
  for (int kt = 0; kt < NKT; kt++) {
    int bnext = bcur + 2; if (bnext > 2) bnext -= 3;
    int ksrc = kt + 2 < NKT ? kt + 2 : NKT - 1;
    stage(bnext, ksrc);
    const char* pa = (const char*)&lA[bcur][0];
    const char* pb = (const char*)&lB[bcur][0];
    s16x8 af[MF], bfr[4];
#pragma unroll
    for (int nf = 0; nf < 4; nf++) bfr[nf] = *(const s16x8*)(pb + boff[nf]);
#pragma unroll
    for (int mf = 0; mf < MF; mf++) af[mf] = *(const s16x8*)(pa + aoff[mf]);
    __builtin_amdgcn_s_setprio(1);
#pragma unroll
    for (int mf = 0; mf < MF; mf++)
#pragma unroll
      for (int nf = 0; nf < 4; nf++)
        acc[mf][nf] = MFMA16(af[mf], bfr[nf], acc[mf][nf], 0, 0, 0);
    __builtin_amdgcn_s_setprio(0);
    if constexpr (MODE == 0) asm volatile("s_waitcnt vmcnt(4)" ::: "memory");
    else                     asm volatile("s_waitcnt vmcnt(3)" ::: "memory");
    __builtin_amdgcn_s_barrier();
    bcur = bcur + 1; if (bcur > 2) bcur -= 3;
  }

  // ---- epilogue ----
#pragma unroll
  for (int mf = 0; mf < MF; mf++) {
#pragma unroll
    for (int nf = 0; nf < 4; nf++) {
#pragma unroll
      for (int i = 0; i < 4; i++) {
        float v = acc[mf][nf][i];
        int mm = m0 + wm * (BM / 2) + mf * 16 + lg * 4 + i;
        int nn = n0 + wn * 64 + nf * 16 + l15;
        if (MODE == 0) {
          int wsel = nn >> 11, n2 = nn & 2047;
          int h = n2 >> 7, dh = n2 & (HD - 1);
          int b = mm >> 11, s2 = mm & (SQ - 1);
          Obf[(size_t)wsel * MR * HD * NH +
              ((size_t)(b * NH + h) * SQ + s2) * HD + dh] = f2bf(v);
        } else {
          Ofp[(size_t)mm * DIMD + nn] = v;
        }
      }
    }
  }
}

// ---------------- flash attention (swapped QK^T, in-lane softmax) ----------
__global__ __launch_bounds__(512, 4) void attn_kernel(
    const u16* __restrict__ Q, const u16* __restrict__ K,
    const u16* __restrict__ Vt, u16* __restrict__ Aout) {
  __shared__ alignas(16) u16 Ksh[2][KBLK * HD];   // 2 x 16 KB
  __shared__ alignas(16) u16 Vsh[2][HD * KBLK];   // 2 x 16 KB
  __shared__ alignas(16) u16 Pl[8][16 * KBLK];    // 16 KB (per-wave, swizzled)
  int t = threadIdx.x;
  int wid = t >> 6, l = t & 63, l15 = l & 15, lg = l >> 4;
  int orig = blockIdx.x;
  int bid = (orig & 7) * 64 + (orig >> 3);
  int qb = bid & 15, bh = bid >> 4;
  int q0 = qb * QBLK + wid * 16;
  const u16* Qb = Q + ((size_t)bh * SQ + q0) * HD;
  const u16* Kb = K + (size_t)bh * SQ * HD;
  const u16* Vb = Vt + (size_t)bh * HD * SQ;

  s16x8 qf[4];
#pragma unroll
  for (int ks = 0; ks < 4; ks++)
    qf[ks] = *(const s16x8*)(Qb + (size_t)l15 * HD + ks * 32 + lg * 8);

  int o0 = t * 16, o1 = t * 16 + 8192;
  int kr0 = o0 >> 8, kc0 = (o0 & 255) ^ ((kr0 & 7) << 4);
  int kr1 = o1 >> 8, kc1 = (o1 & 255) ^ ((kr1 & 7) << 4);
  int vr0 = o0 >> 7, vc0 = (o0 & 127) ^ ((vr0 & 7) << 4);
  int vr1 = o1 >> 7, vc1 = (o1 & 127) ^ ((vr1 & 7) << 4);

  auto stage = [&](int buf, int kb) {
    const u16* Kt = Kb + (size_t)kb * KBLK * HD;
    const u16* Vs = Vb + kb * KBLK;
    gld16(Kt + (size_t)kr0 * HD + (kc0 >> 1), &Ksh[buf][o0 >> 1]);
    gld16(Kt + (size_t)kr1 * HD + (kc1 >> 1), &Ksh[buf][o1 >> 1]);
    gld16(Vs + (size_t)vr0 * SQ + (vc0 >> 1), &Vsh[buf][o0 >> 1]);
    gld16(Vs + (size_t)vr1 * SQ + (vc1 >> 1), &Vsh[buf][o1 >> 1]);
  };

  f32x4 acc[8];
#pragma unroll
  for (int i = 0; i < 8; i++) acc[i] = (f32x4){0.f, 0.f, 0.f, 0.f};
  float m = -3.0e38f, lsum = 0.f;

  stage(0, 0);
  __syncthreads();

#pragma unroll 1
  for (int kb = 0; kb < SQ / KBLK; kb++) {
    int cur = kb & 1;
    if (kb + 1 < SQ / KBLK) stage(cur ^ 1, kb + 1);
    f32x4 sa[4];
#pragma unroll
    for (int cb = 0; cb < 4; cb++) sa[cb] = (f32x4){0.f, 0.f, 0.f, 0.f};
    __builtin_amdgcn_s_setprio(1);
#pragma unroll
    for (int ks = 0; ks < 4; ks++) {
#pragma unroll
      for (int cb = 0; cb < 4; cb++) {
        int r = cb * 16 + l15;
        int off = r * 256 + ((ks * 64 + lg * 16) ^ ((r & 7) << 4));
        s16x8 kf = *(const s16x8*)((const char*)&Ksh[cur][0] + off);
        sa[cb] = MFMA16(kf, qf[ks], sa[cb], 0, 0, 0);
      }
    }
    __builtin_amdgcn_s_setprio(0);
    float rm = sa[0][0];
#pragma unroll
    for (int cb = 0; cb < 4; cb++)
#pragma unroll
      for (int i = 0; i < 4; i++) rm = fmaxf(rm, sa[cb][i]);
    rm = fmaxf(rm, __shfl_xor(rm, 16));
    rm = fmaxf(rm, __shfl_xor(rm, 32));
    if (!__all(rm <= m + 8.0f)) {
      float mn = fmaxf(m, rm);
      float al = __expf(m - mn);
      m = mn;
      float alq[4];
#pragma unroll
      for (int i = 0; i < 4; i++) alq[i] = __shfl(al, lg * 4 + i, 16);
#pragma unroll
      for (int c2 = 0; c2 < 8; c2++)
#pragma unroll
        for (int i = 0; i < 4; i++) acc[c2][i] *= alq[i];
      lsum *= al;
    }
    float ps = 0.f;
#pragma unroll
    for (int cb = 0; cb < 4; cb++)
#pragma unroll
      for (int i = 0; i < 4; i++) {
        sa[cb][i] = __expf(sa[cb][i] - m);
        ps += sa[cb][i];
      }
    ps += __shfl_xor(ps, 16);
    ps += __shfl_xor(ps, 32);
    lsum += ps;
#pragma unroll
    for (int cb = 0; cb < 4; cb++) {
      u32 lo = (u32)f2bf(sa[cb][0]) | ((u32)f2bf(sa[cb][1]) << 16);
      u32 hi = (u32)f2bf(sa[cb][2]) | ((u32)f2bf(sa[cb][3]) << 16);
      int off = l15 * 128 + ((cb * 32 + lg * 8) ^ ((l15 & 7) << 4));
      *(uint2*)((char*)&Pl[wid][0] + off) = make_uint2(lo, hi);
    }
    asm volatile("s_waitcnt lgkmcnt(0)" ::: "memory");
    __builtin_amdgcn_sched_barrier(0);
    s16x8 pf[2];
#pragma unroll
    for (int k2 = 0; k2 < 2; k2++) {
      int off = l15 * 128 + ((k2 * 64 + lg * 16) ^ ((l15 & 7) << 4));
      pf[k2] = *(const s16x8*)((const char*)&Pl[wid][0] + off);
    }
    __builtin_amdgcn_s_setprio(1);
#pragma unroll
    for (int c2 = 0; c2 < 8; c2++) {
#pragma unroll
      for (int k2 = 0; k2 < 2; k2++) {
        int r = c2 * 16 + l15;
        int off = r * 128 + ((k2 * 64 + lg * 16) ^ ((r & 7) << 4));
        s16x8 vf = *(const s16x8*)((const char*)&Vsh[cur][0] + off);
        acc[c2] = MFMA16(pf[k2], vf, acc[c2], 0, 0, 0);
      }
    }
    __builtin_amdgcn_s_setprio(0);
    __syncthreads();
  }
  float rin = 1.0f / lsum;
  float rq[4];
#pragma unroll
  for (int i = 0; i < 4; i++) rq[i] = __shfl(rin, lg * 4 + i, 16);
  int b = bh >> 4, h = bh & (NH - 1);
#pragma unroll
  for (int c2 = 0; c2 < 8; c2++) {
#pragma unroll
    for (int i = 0; i < 4; i++) {
      int q = q0 + lg * 4 + i;
      int dh = c2 * 16 + l15;
      Aout[((size_t)b * SQ + q) * DIMD + h * HD + dh] = f2bf(acc[c2][i] * rq[i]);
    }
  }
}

extern "C" void kernel_launch(void* const* d_in, const int* in_sizes, int n_in,
                              void* d_out, int out_size, void* d_ws, size_t ws_size,
                              hipStream_t stream) {
  (void)in_sizes; (void)n_in; (void)out_size; (void)ws_size;
  const float* x    = (const float*)d_in[0];
  const float* wq   = (const float*)d_in[1];
  const float* wk   = (const float*)d_in[2];
  const float* wv   = (const float*)d_in[3];
  const float* wo   = (const float*)d_in[4];
  const float* cosT = (const float*)d_in[5];
  const float* sinT = (const float*)d_in[6];
  float* out = (float*)d_out;

  char* p = (char*)d_ws;
  const size_t SZ_MD = (size_t)MR * DIMD * 2;    // 16.78 MB
  const size_t SZ_W  = (size_t)DIMD * DIMD * 2;  // 8.39 MB
  u16* xb   = (u16*)p; p += SZ_MD;
  u16* wqb  = (u16*)p; p += SZ_W;   // wq,wk,wv contiguous => one N=6144 GEMM
  u16* wkb  = (u16*)p; p += SZ_W;
  u16* wvb  = (u16*)p; p += SZ_W;
  u16* wob  = (u16*)p; p += SZ_W;
  u16* Qraw = (u16*)p; p += SZ_MD;  // Qraw,Kraw,Vraw contiguous (wsel scatter)
  u16* Kraw = (u16*)p; p += SZ_MD;
  u16* Vraw = (u16*)p; p += SZ_MD;
  u16* Qr   = (u16*)p; p += SZ_MD;
  u16* Kr   = (u16*)p; p += SZ_MD;
  u16* Vt   = (u16*)p; p += SZ_MD;
  u16* attnout = Qraw;  // Qraw dead after rope; reuse

  cvt_bf16<<<1024, 256, 0, stream>>>(x,  xb,  MR * DIMD / 4);
  cvt_bf16<<<512,  256, 0, stream>>>(wq, wqb, DIMD * DIMD / 4);
  cvt_bf16<<<512,  256, 0, stream>>>(wk, wkb, DIMD * DIMD / 4);
  cvt_bf16<<<512,  256, 0, stream>>>(wv, wvb, DIMD * DIMD / 4);
  cvt_bf16<<<512,  256, 0, stream>>>(wo, wob, DIMD * DIMD / 4);

  gemm_tb<0><<<384, 512, 0, stream>>>(xb, wqb, Qraw, nullptr);
  rope_kernel<<<dim3(16384, 2), 256, 0, stream>>>(Qraw, Kraw, Qr, Kr, cosT, sinT);
  transpose_v<<<dim3(32, 2, 32), 256, 0, stream>>>(Vraw, Vt);
  attn_kernel<<<512, 512, 0, stream>>>(Qr, Kr, Vt, attnout);
  gemm_tb<1><<<256, 512, 0, stream>>>(attnout, wob, nullptr, out);
}

// Round 7
// 321.971 us; speedup vs baseline: 1.2156x; 1.2156x over previous
//
#include <hip/hip_runtime.h>

#define SQ   2048
#define DIMD 2048
#define NH   16
#define HD   128
#define MR   4096   // B*S
#define QBLK 128
#define KBLK 64

using u16 = unsigned short;
using u32 = unsigned int;
using s16x8 = __attribute__((ext_vector_type(8))) short;
using u16x8 = __attribute__((ext_vector_type(8))) unsigned short;
using f32x4 = __attribute__((ext_vector_type(4))) float;
using as3u  = __attribute__((address_space(3))) u32;
using as1u  = __attribute__((address_space(1))) u32;

__device__ __forceinline__ u16 f2bf(float f) {
  u32 x = __float_as_uint(f);
  return (u16)((x + 0x7fffu + ((x >> 16) & 1u)) >> 16);
}
__device__ __forceinline__ float bf2f(u16 u) {
  return __uint_as_float(((u32)u) << 16);
}
__device__ __forceinline__ void gld16(const void* g, void* l) {
  __builtin_amdgcn_global_load_lds((as1u*)g, (as3u*)l, 16, 0, 0);
}
#define MFMA16 __builtin_amdgcn_mfma_f32_16x16x32_bf16

// ---------------- fp32 -> bf16 convert (x) ----------------
__global__ __launch_bounds__(256) void cvt_bf16(const float* __restrict__ s,
                                                u16* __restrict__ d, int n4) {
  int i = blockIdx.x * 256 + threadIdx.x;
  int st = gridDim.x * 256;
  for (; i < n4; i += st) {
    float4 v = ((const float4*)s)[i];
    u32 lo = (u32)f2bf(v.x) | ((u32)f2bf(v.y) << 16);
    u32 hi = (u32)f2bf(v.z) | ((u32)f2bf(v.w) << 16);
    ((uint2*)d)[i] = make_uint2(lo, hi);
  }
}

// ---------------- fp32 -> bf16 convert, 4 weights in one launch -------------
__global__ __launch_bounds__(256) void cvt_w4(const float* __restrict__ w0,
                                              const float* __restrict__ w1,
                                              const float* __restrict__ w2,
                                              const float* __restrict__ w3,
                                              u16* __restrict__ d) {
  const int n4 = DIMD * DIMD / 4;
  int y = blockIdx.y;
  const float* s = (y == 0) ? w0 : (y == 1) ? w1 : (y == 2) ? w2 : w3;
  u16* dst = d + (size_t)y * DIMD * DIMD;
  int i = blockIdx.x * 256 + threadIdx.x;
  int st = gridDim.x * 256;
  for (; i < n4; i += st) {
    float4 v = ((const float4*)s)[i];
    u32 lo = (u32)f2bf(v.x) | ((u32)f2bf(v.y) << 16);
    u32 hi = (u32)f2bf(v.z) | ((u32)f2bf(v.w) << 16);
    ((uint2*)dst)[i] = make_uint2(lo, hi);
  }
}

// ---------------- RoPE (1 wave = 1 row of 128) ----------------
__global__ __launch_bounds__(256) void rope_kernel(
    const u16* __restrict__ Qin, const u16* __restrict__ Kin,
    u16* __restrict__ Qout, u16* __restrict__ Kout,
    const float* __restrict__ cosT, const float* __restrict__ sinT) {
  int ten = blockIdx.y;
  const u16* in = ten ? Kin : Qin;
  u16* outp     = ten ? Kout : Qout;
  float scl     = ten ? 1.0f : 0.08838834764831845f;  // fold 1/sqrt(DH) into Q
  int row = blockIdx.x * 4 + (threadIdx.x >> 6);
  int j   = threadIdx.x & 63;
  int s   = row & (SQ - 1);
  const u16* r = in + (size_t)row * HD;
  u16* w = outp + (size_t)row * HD;
  float c  = cosT[s * HD + j];
  float si = sinT[s * HD + j];
  float a  = bf2f(r[j]);
  float b  = bf2f(r[j + 64]);
  float ev = bf2f(r[2 * j]);
  float od = bf2f(r[2 * j + 1]);
  w[j]      = f2bf((a * c - od * si) * scl);
  w[j + 64] = f2bf((b * c + ev * si) * scl);
}

// ---------------- V (b,h,s,dh) -> Vt (b,h,dh,s) ----------------
__global__ __launch_bounds__(256) void transpose_v(const u16* __restrict__ V,
                                                   u16* __restrict__ Vt) {
  __shared__ u16 tile[64][72];
  int sb = blockIdx.x, db = blockIdx.y, bh = blockIdx.z;
  int r  = threadIdx.x >> 3;
  int c8 = (threadIdx.x & 7) * 8;
  const u16* src = V + ((size_t)bh * SQ + sb * 64) * HD + db * 64;
#pragma unroll
  for (int p2 = 0; p2 < 2; p2++) {
    int row = p2 * 32 + r;
    u16x8 v = *(const u16x8*)(src + (size_t)row * HD + c8);
#pragma unroll
    for (int k2 = 0; k2 < 8; k2++) tile[row][c8 + k2] = v[k2];
  }
  __syncthreads();
  u16* dst = Vt + ((size_t)bh * HD + db * 64) * SQ + sb * 64;
#pragma unroll
  for (int p2 = 0; p2 < 2; p2++) {
    int dr = p2 * 32 + r;
    u16x8 o;
#pragma unroll
    for (int k2 = 0; k2 < 8; k2++) o[k2] = tile[c8 + k2][dr];
    *(u16x8*)(dst + (size_t)dr * SQ + c8) = o;
  }
}

// ---------------- GEMM C = A(M,K) * W(N,K)^T  (m97 structure, PROVEN r3) ----
// MODE 0: QKV -> bf16, scattered to (b,h,s,dh); select W/out by blockIdx.y
// MODE 1: O-proj -> fp32 row-major
template <int MODE>
__global__ __launch_bounds__(256) void gemm_bt(
    const u16* __restrict__ A,
    const u16* __restrict__ W0, const u16* __restrict__ W1, const u16* __restrict__ W2,
    u16* __restrict__ O0, u16* __restrict__ O1, u16* __restrict__ O2,
    float* __restrict__ Ofp) {
  __shared__ alignas(16) u16 lA[2][128 * 32];
  __shared__ alignas(16) u16 lB[2][128 * 32];
  int t = threadIdx.x;
  int l = t & 63, l15 = l & 15, lg = l >> 4;
  int wid = t >> 6, wr = wid >> 1, wc = wid & 1;
  int mi = blockIdx.x >> 4, ni = blockIdx.x & 15;
  int m0 = mi * 128, n0 = ni * 128;
  const u16* W = W0;
  u16* Ob = O0;
  if (MODE == 0) {
    if (blockIdx.y == 1) { W = W1; Ob = O1; }
    else if (blockIdx.y == 2) { W = W2; Ob = O2; }
  }
  const u16* Ag = A + (size_t)m0 * DIMD;
  const u16* Wg = W + (size_t)n0 * DIMD;
  int r0 = t >> 2, ch = (t & 3) * 8;

  f32x4 acc[4][4];
#pragma unroll
  for (int a1 = 0; a1 < 4; a1++)
#pragma unroll
    for (int b1 = 0; b1 < 4; b1++) acc[a1][b1] = (f32x4){0.f, 0.f, 0.f, 0.f};

  auto stage = [&](int buf, int kb) {
    int k0 = kb * 32;
    gld16(Ag + (size_t)r0 * DIMD + k0 + ch,        &lA[buf][t * 8]);
    gld16(Ag + (size_t)(r0 + 64) * DIMD + k0 + ch, &lA[buf][(t + 256) * 8]);
    gld16(Wg + (size_t)r0 * DIMD + k0 + ch,        &lB[buf][t * 8]);
    gld16(Wg + (size_t)(r0 + 64) * DIMD + k0 + ch, &lB[buf][(t + 256) * 8]);
  };

  stage(0, 0);
  __syncthreads();
#pragma unroll 2
  for (int kb = 0; kb < DIMD / 32; kb++) {
    if (kb + 1 < DIMD / 32) stage((kb + 1) & 1, kb + 1);
    int buf = kb & 1;
    s16x8 af[4], bfr[4];
#pragma unroll
    for (int rb = 0; rb < 4; rb++)
      af[rb] = *(const s16x8*)&lA[buf][(wr * 64 + rb * 16 + l15) * 32 + lg * 8];
#pragma unroll
    for (int cb = 0; cb < 4; cb++)
      bfr[cb] = *(const s16x8*)&lB[buf][(wc * 64 + cb * 16 + l15) * 32 + lg * 8];
#pragma unroll
    for (int rb = 0; rb < 4; rb++)
#pragma unroll
      for (int cb = 0; cb < 4; cb++)
        acc[rb][cb] = MFMA16(af[rb], bfr[cb], acc[rb][cb], 0, 0, 0);
    __syncthreads();
  }
#pragma unroll
  for (int rb = 0; rb < 4; rb++) {
#pragma unroll
    for (int cb = 0; cb < 4; cb++) {
#pragma unroll
      for (int i = 0; i < 4; i++) {
        float v = acc[rb][cb][i];
        int mm = m0 + wr * 64 + rb * 16 + lg * 4 + i;
        int nn = n0 + wc * 64 + cb * 16 + l15;
        if (MODE == 0) {
          int b = mm >> 11, s2 = mm & (SQ - 1), h = nn >> 7, dh = nn & (HD - 1);
          Ob[((size_t)(b * NH + h) * SQ + s2) * HD + dh] = f2bf(v);
        } else {
          Ofp[(size_t)mm * DIMD + nn] = v;
        }
      }
    }
  }
}

// ---------------- flash attention (swapped QK^T, in-lane softmax) ----------
// grid: 512 blocks (XCD-swizzled). 8 waves/block, wave owns 16 q-rows.
// P LDS round-trip uses plain C++ LDS ops -> compiler emits minimal counted
// lgkm waits itself (manual full-drain + sched_barrier removed this round).
__global__ __launch_bounds__(512, 4) void attn_kernel(
    const u16* __restrict__ Q, const u16* __restrict__ K,
    const u16* __restrict__ Vt, u16* __restrict__ Aout) {
  __shared__ alignas(16) u16 Ksh[2][KBLK * HD];   // 2 x 16 KB
  __shared__ alignas(16) u16 Vsh[2][HD * KBLK];   // 2 x 16 KB
  __shared__ alignas(16) u16 Pl[8][16 * KBLK];    // 16 KB (per-wave, swizzled)
  int t = threadIdx.x;
  int wid = t >> 6, l = t & 63, l15 = l & 15, lg = l >> 4;
  int orig = blockIdx.x;
  int bid = (orig & 7) * 64 + (orig >> 3);
  int qb = bid & 15, bh = bid >> 4;
  int q0 = qb * QBLK + wid * 16;
  const u16* Qb = Q + ((size_t)bh * SQ + q0) * HD;
  const u16* Kb = K + (size_t)bh * SQ * HD;
  const u16* Vb = Vt + (size_t)bh * HD * SQ;

  s16x8 qf[4];
#pragma unroll
  for (int ks = 0; ks < 4; ks++)
    qf[ks] = *(const s16x8*)(Qb + (size_t)l15 * HD + ks * 32 + lg * 8);

  int o0 = t * 16, o1 = t * 16 + 8192;
  int kr0 = o0 >> 8, kc0 = (o0 & 255) ^ ((kr0 & 7) << 4);
  int kr1 = o1 >> 8, kc1 = (o1 & 255) ^ ((kr1 & 7) << 4);
  int vr0 = o0 >> 7, vc0 = (o0 & 127) ^ ((vr0 & 7) << 4);
  int vr1 = o1 >> 7, vc1 = (o1 & 127) ^ ((vr1 & 7) << 4);

  auto stage = [&](int buf, int kb) {
    const u16* Kt = Kb + (size_t)kb * KBLK * HD;
    const u16* Vs = Vb + kb * KBLK;
    gld16(Kt + (size_t)kr0 * HD + (kc0 >> 1), &Ksh[buf][o0 >> 1]);
    gld16(Kt + (size_t)kr1 * HD + (kc1 >> 1), &Ksh[buf][o1 >> 1]);
    gld16(Vs + (size_t)vr0 * SQ + (vc0 >> 1), &Vsh[buf][o0 >> 1]);
    gld16(Vs + (size_t)vr1 * SQ + (vc1 >> 1), &Vsh[buf][o1 >> 1]);
  };

  f32x4 acc[8];
#pragma unroll
  for (int i = 0; i < 8; i++) acc[i] = (f32x4){0.f, 0.f, 0.f, 0.f};
  float m = -3.0e38f, lsum = 0.f;

  stage(0, 0);
  __syncthreads();

#pragma unroll 1
  for (int kb = 0; kb < SQ / KBLK; kb++) {
    int cur = kb & 1;
    if (kb + 1 < SQ / KBLK) stage(cur ^ 1, kb + 1);
    // ---- S^T = K . Q^T : rows k (cb*16+lg*4+i), cols q (l15) ----
    f32x4 sa[4];
#pragma unroll
    for (int cb = 0; cb < 4; cb++) sa[cb] = (f32x4){0.f, 0.f, 0.f, 0.f};
    __builtin_amdgcn_s_setprio(1);
#pragma unroll
    for (int ks = 0; ks < 4; ks++) {
#pragma unroll
      for (int cb = 0; cb < 4; cb++) {
        int r = cb * 16 + l15;
        int off = r * 256 + ((ks * 64 + lg * 16) ^ ((r & 7) << 4));
        s16x8 kf = *(const s16x8*)((const char*)&Ksh[cur][0] + off);
        sa[cb] = MFMA16(kf, qf[ks], sa[cb], 0, 0, 0);
      }
    }
    __builtin_amdgcn_s_setprio(0);
    // ---- row stats: lane l15 owns q-row l15 ----
    float rm = sa[0][0];
#pragma unroll
    for (int cb = 0; cb < 4; cb++)
#pragma unroll
      for (int i = 0; i < 4; i++) rm = fmaxf(rm, sa[cb][i]);
    rm = fmaxf(rm, __shfl_xor(rm, 16));
    rm = fmaxf(rm, __shfl_xor(rm, 32));
    if (!__all(rm <= m + 8.0f)) {   // defer-max
      float mn = fmaxf(m, rm);
      float al = __expf(m - mn);
      m = mn;
      float alq[4];
#pragma unroll
      for (int i = 0; i < 4; i++) alq[i] = __shfl(al, lg * 4 + i, 16);
#pragma unroll
      for (int c2 = 0; c2 < 8; c2++)
#pragma unroll
        for (int i = 0; i < 4; i++) acc[c2][i] *= alq[i];
      lsum *= al;
    }
    float ps = 0.f;
#pragma unroll
    for (int cb = 0; cb < 4; cb++)
#pragma unroll
      for (int i = 0; i < 4; i++) {
        sa[cb][i] = __expf(sa[cb][i] - m);
        ps += sa[cb][i];
      }
    ps += __shfl_xor(ps, 16);
    ps += __shfl_xor(ps, 32);
    lsum += ps;
    // ---- P -> per-wave LDS: row q=l15, cols k; packed 8B, swizzled ----
#pragma unroll
    for (int cb = 0; cb < 4; cb++) {
      u32 lo = (u32)f2bf(sa[cb][0]) | ((u32)f2bf(sa[cb][1]) << 16);
      u32 hi = (u32)f2bf(sa[cb][2]) | ((u32)f2bf(sa[cb][3]) << 16);
      int off = l15 * 128 + ((cb * 32 + lg * 8) ^ ((l15 & 7) << 4));
      *(uint2*)((char*)&Pl[wid][0] + off) = make_uint2(lo, hi);
    }
    s16x8 pf[2];
#pragma unroll
    for (int k2 = 0; k2 < 2; k2++) {
      int off = l15 * 128 + ((k2 * 64 + lg * 16) ^ ((l15 & 7) << 4));
      pf[k2] = *(const s16x8*)((const char*)&Pl[wid][0] + off);
    }
    // ---- PV: out 16 q-rows x 128 dh ----
    __builtin_amdgcn_s_setprio(1);
#pragma unroll
    for (int c2 = 0; c2 < 8; c2++) {
#pragma unroll
      for (int k2 = 0; k2 < 2; k2++) {
        int r = c2 * 16 + l15;
        int off = r * 128 + ((k2 * 64 + lg * 16) ^ ((r & 7) << 4));
        s16x8 vf = *(const s16x8*)((const char*)&Vsh[cur][0] + off);
        acc[c2] = MFMA16(pf[k2], vf, acc[c2], 0, 0, 0);
      }
    }
    __builtin_amdgcn_s_setprio(0);
    __syncthreads();
  }
  float rin = 1.0f / lsum;
  float rq[4];
#pragma unroll
  for (int i = 0; i < 4; i++) rq[i] = __shfl(rin, lg * 4 + i, 16);
  int b = bh >> 4, h = bh & (NH - 1);
#pragma unroll
  for (int c2 = 0; c2 < 8; c2++) {
#pragma unroll
    for (int i = 0; i < 4; i++) {
      int q = q0 + lg * 4 + i;
      int dh = c2 * 16 + l15;
      Aout[((size_t)b * SQ + q) * DIMD + h * HD + dh] = f2bf(acc[c2][i] * rq[i]);
    }
  }
}

extern "C" void kernel_launch(void* const* d_in, const int* in_sizes, int n_in,
                              void* d_out, int out_size, void* d_ws, size_t ws_size,
                              hipStream_t stream) {
  (void)in_sizes; (void)n_in; (void)out_size; (void)ws_size;
  const float* x    = (const float*)d_in[0];
  const float* wq   = (const float*)d_in[1];
  const float* wk   = (const float*)d_in[2];
  const float* wv   = (const float*)d_in[3];
  const float* wo   = (const float*)d_in[4];
  const float* cosT = (const float*)d_in[5];
  const float* sinT = (const float*)d_in[6];
  float* out = (float*)d_out;

  char* p = (char*)d_ws;
  const size_t SZ_MD = (size_t)MR * DIMD * 2;    // 16.78 MB
  const size_t SZ_W  = (size_t)DIMD * DIMD * 2;  // 8.39 MB
  u16* xb   = (u16*)p; p += SZ_MD;
  u16* wqb  = (u16*)p; p += SZ_W;   // wq,wk,wv,wo contiguous (cvt_w4)
  u16* wkb  = (u16*)p; p += SZ_W;
  u16* wvb  = (u16*)p; p += SZ_W;
  u16* wob  = (u16*)p; p += SZ_W;
  u16* Qraw = (u16*)p; p += SZ_MD;
  u16* Kraw = (u16*)p; p += SZ_MD;
  u16* Qr   = (u16*)p; p += SZ_MD;
  u16* Kr   = (u16*)p; p += SZ_MD;
  u16* Vraw = (u16*)p; p += SZ_MD;
  u16* Vt   = (u16*)p; p += SZ_MD;
  u16* attnout = Qraw;  // Qraw dead after rope; reuse

  cvt_bf16<<<1024, 256, 0, stream>>>(x, xb, MR * DIMD / 4);
  cvt_w4<<<dim3(512, 4), 256, 0, stream>>>(wq, wk, wv, wo, wqb);

  gemm_bt<0><<<dim3(512, 3), 256, 0, stream>>>(xb, wqb, wkb, wvb, Qraw, Kraw, Vraw, nullptr);
  rope_kernel<<<dim3(16384, 2), 256, 0, stream>>>(Qraw, Kraw, Qr, Kr, cosT, sinT);
  transpose_v<<<dim3(32, 2, 32), 256, 0, stream>>>(Vraw, Vt);
  attn_kernel<<<512, 512, 0, stream>>>(Qr, Kr, Vt, attnout);
  gemm_bt<1><<<dim3(512, 1), 256, 0, stream>>>(attnout, wob, nullptr, nullptr,
                                               nullptr, nullptr, nullptr, out);
}

// Round 8
// 311.337 us; speedup vs baseline: 1.2571x; 1.0342x over previous
//
#include <hip/hip_runtime.h>

#define SQ   2048
#define DIMD 2048
#define NH   16
#define HD   128
#define MR   4096   // B*S
#define QBLK 128
#define KBLK 64

using u16 = unsigned short;
using u32 = unsigned int;
using s16x8 = __attribute__((ext_vector_type(8))) short;
using u16x8 = __attribute__((ext_vector_type(8))) unsigned short;
using f32x4 = __attribute__((ext_vector_type(4))) float;
using as3u  = __attribute__((address_space(3))) u32;
using as1u  = __attribute__((address_space(1))) u32;

__device__ __forceinline__ u16 f2bf(float f) {
  u32 x = __float_as_uint(f);
  return (u16)((x + 0x7fffu + ((x >> 16) & 1u)) >> 16);
}
__device__ __forceinline__ float bf2f(u16 u) {
  return __uint_as_float(((u32)u) << 16);
}
__device__ __forceinline__ void gld16(const void* g, void* l) {
  __builtin_amdgcn_global_load_lds((as1u*)g, (as3u*)l, 16, 0, 0);
}
#define MFMA16 __builtin_amdgcn_mfma_f32_16x16x32_bf16

// ---------------- fp32 -> bf16 convert (x) ----------------
__global__ __launch_bounds__(256) void cvt_bf16(const float* __restrict__ s,
                                                u16* __restrict__ d, int n4) {
  int i = blockIdx.x * 256 + threadIdx.x;
  int st = gridDim.x * 256;
  for (; i < n4; i += st) {
    float4 v = ((const float4*)s)[i];
    u32 lo = (u32)f2bf(v.x) | ((u32)f2bf(v.y) << 16);
    u32 hi = (u32)f2bf(v.z) | ((u32)f2bf(v.w) << 16);
    ((uint2*)d)[i] = make_uint2(lo, hi);
  }
}

// ---------------- fp32 -> bf16 convert, 4 weights in one launch -------------
__global__ __launch_bounds__(256) void cvt_w4(const float* __restrict__ w0,
                                              const float* __restrict__ w1,
                                              const float* __restrict__ w2,
                                              const float* __restrict__ w3,
                                              u16* __restrict__ d) {
  const int n4 = DIMD * DIMD / 4;
  int y = blockIdx.y;
  const float* s = (y == 0) ? w0 : (y == 1) ? w1 : (y == 2) ? w2 : w3;
  u16* dst = d + (size_t)y * DIMD * DIMD;
  int i = blockIdx.x * 256 + threadIdx.x;
  int st = gridDim.x * 256;
  for (; i < n4; i += st) {
    float4 v = ((const float4*)s)[i];
    u32 lo = (u32)f2bf(v.x) | ((u32)f2bf(v.y) << 16);
    u32 hi = (u32)f2bf(v.z) | ((u32)f2bf(v.w) << 16);
    ((uint2*)dst)[i] = make_uint2(lo, hi);
  }
}

// ---------------- RoPE (1 wave = 1 row of 128) ----------------
__global__ __launch_bounds__(256) void rope_kernel(
    const u16* __restrict__ Qin, const u16* __restrict__ Kin,
    u16* __restrict__ Qout, u16* __restrict__ Kout,
    const float* __restrict__ cosT, const float* __restrict__ sinT) {
  int ten = blockIdx.y;
  const u16* in = ten ? Kin : Qin;
  u16* outp     = ten ? Kout : Qout;
  float scl     = ten ? 1.0f : 0.08838834764831845f;  // fold 1/sqrt(DH) into Q
  int row = blockIdx.x * 4 + (threadIdx.x >> 6);
  int j   = threadIdx.x & 63;
  int s   = row & (SQ - 1);
  const u16* r = in + (size_t)row * HD;
  u16* w = outp + (size_t)row * HD;
  float c  = cosT[s * HD + j];
  float si = sinT[s * HD + j];
  float a  = bf2f(r[j]);
  float b  = bf2f(r[j + 64]);
  float ev = bf2f(r[2 * j]);
  float od = bf2f(r[2 * j + 1]);
  w[j]      = f2bf((a * c - od * si) * scl);
  w[j + 64] = f2bf((b * c + ev * si) * scl);
}

// ---------------- GEMM C = A(M,K) * W(N,K)^T  (m97 structure, proven) -------
// MODE 0: QKV. blockIdx.y selects W/out. y=0,1 (Q,K): bf16 scatter (b,h,s,dh).
//         y=2 (V): epilogue transposes the 128s x 128dh head-tile through LDS
//         and writes Vt (b,h,dh,s) directly (transpose_v kernel eliminated).
// MODE 1: O-proj -> fp32 row-major.
template <int MODE>
__global__ __launch_bounds__(256) void gemm_bt(
    const u16* __restrict__ A,
    const u16* __restrict__ W0, const u16* __restrict__ W1, const u16* __restrict__ W2,
    u16* __restrict__ O0, u16* __restrict__ O1, u16* __restrict__ O2,
    float* __restrict__ Ofp) {
  // 34 KB shared: staging lA/lB (32 KB) + alias as 128x132 transpose buffer
  __shared__ alignas(16) u16 SM[17408];
  u16* lA = SM;          // [2][4096]
  u16* lB = SM + 8192;   // [2][4096]
  int t = threadIdx.x;
  int l = t & 63, l15 = l & 15, lg = l >> 4;
  int wid = t >> 6, wr = wid >> 1, wc = wid & 1;
  int mi = blockIdx.x >> 4, ni = blockIdx.x & 15;
  int m0 = mi * 128, n0 = ni * 128;
  const u16* W = W0;
  u16* Ob = O0;
  if (MODE == 0) {
    if (blockIdx.y == 1) { W = W1; Ob = O1; }
    else if (blockIdx.y == 2) { W = W2; Ob = O2; }
  }
  const u16* Ag = A + (size_t)m0 * DIMD;
  const u16* Wg = W + (size_t)n0 * DIMD;
  int r0 = t >> 2, ch = (t & 3) * 8;

  f32x4 acc[4][4];
#pragma unroll
  for (int a1 = 0; a1 < 4; a1++)
#pragma unroll
    for (int b1 = 0; b1 < 4; b1++) acc[a1][b1] = (f32x4){0.f, 0.f, 0.f, 0.f};

  auto stage = [&](int buf, int kb) {
    int k0 = kb * 32;
    gld16(Ag + (size_t)r0 * DIMD + k0 + ch,        &lA[buf * 4096 + t * 8]);
    gld16(Ag + (size_t)(r0 + 64) * DIMD + k0 + ch, &lA[buf * 4096 + (t + 256) * 8]);
    gld16(Wg + (size_t)r0 * DIMD + k0 + ch,        &lB[buf * 4096 + t * 8]);
    gld16(Wg + (size_t)(r0 + 64) * DIMD + k0 + ch, &lB[buf * 4096 + (t + 256) * 8]);
  };

  stage(0, 0);
  __syncthreads();
#pragma unroll 2
  for (int kb = 0; kb < DIMD / 32; kb++) {
    if (kb + 1 < DIMD / 32) stage((kb + 1) & 1, kb + 1);
    int buf = kb & 1;
    s16x8 af[4], bfr[4];
#pragma unroll
    for (int rb = 0; rb < 4; rb++)
      af[rb] = *(const s16x8*)&lA[buf * 4096 + (wr * 64 + rb * 16 + l15) * 32 + lg * 8];
#pragma unroll
    for (int cb = 0; cb < 4; cb++)
      bfr[cb] = *(const s16x8*)&lB[buf * 4096 + (wc * 64 + cb * 16 + l15) * 32 + lg * 8];
#pragma unroll
    for (int rb = 0; rb < 4; rb++)
#pragma unroll
      for (int cb = 0; cb < 4; cb++)
        acc[rb][cb] = MFMA16(af[rb], bfr[cb], acc[rb][cb], 0, 0, 0);
    __syncthreads();
  }

  if (MODE == 0 && blockIdx.y == 2) {
    // ---- V epilogue: transpose 128s x 128dh head-tile, write Vt (b,h,dh,s)
    u16 (*lT)[132] = (u16(*)[132])SM;
#pragma unroll
    for (int rb = 0; rb < 4; rb++)
#pragma unroll
      for (int cb = 0; cb < 4; cb++)
#pragma unroll
        for (int i = 0; i < 4; i++)
          lT[wr * 64 + rb * 16 + lg * 4 + i][wc * 64 + cb * 16 + l15] =
              f2bf(acc[rb][cb][i]);
    __syncthreads();
    int b = m0 >> 11, s0 = m0 & (SQ - 1), h = n0 >> 7;
    int dh = t >> 1, sc = (t & 1) * 64;
    u16* dst = Ob + ((size_t)(b * NH + h) * HD + dh) * SQ + s0 + sc;
#pragma unroll
    for (int c8 = 0; c8 < 8; c8++) {
      u16x8 o;
#pragma unroll
      for (int e = 0; e < 8; e++) o[e] = lT[sc + c8 * 8 + e][dh];
      *(u16x8*)(dst + c8 * 8) = o;
    }
    return;
  }

#pragma unroll
  for (int rb = 0; rb < 4; rb++) {
#pragma unroll
    for (int cb = 0; cb < 4; cb++) {
#pragma unroll
      for (int i = 0; i < 4; i++) {
        float v = acc[rb][cb][i];
        int mm = m0 + wr * 64 + rb * 16 + lg * 4 + i;
        int nn = n0 + wc * 64 + cb * 16 + l15;
        if (MODE == 0) {
          int b = mm >> 11, s2 = mm & (SQ - 1), h = nn >> 7, dh = nn & (HD - 1);
          Ob[((size_t)(b * NH + h) * SQ + s2) * HD + dh] = f2bf(v);
        } else {
          Ofp[(size_t)mm * DIMD + nn] = v;
        }
      }
    }
  }
}

// ---------------- flash attention (swapped QK^T, 32 q-rows per wave) --------
// 512 blocks x 256 thr (4 waves). Wave owns 32 q-rows as two 16-row
// sub-blocks (mq=0,1): each K-frag / V-frag LDS read now feeds TWO MFMAs
// (halves the dominant LDS-read traffic; kernel was LDS-BW-bound).
__global__ __launch_bounds__(256, 2) void attn_kernel(
    const u16* __restrict__ Q, const u16* __restrict__ K,
    const u16* __restrict__ Vt, u16* __restrict__ Aout) {
  __shared__ alignas(16) u16 Ksh[2][KBLK * HD];   // 2 x 16 KB
  __shared__ alignas(16) u16 Vsh[2][HD * KBLK];   // 2 x 16 KB
  __shared__ alignas(16) u16 Pl[4][32 * KBLK];    // 16 KB (per-wave, swizzled)
  int t = threadIdx.x;
  int wid = t >> 6, l = t & 63, l15 = l & 15, lg = l >> 4;
  int orig = blockIdx.x;
  int bid = (orig & 7) * 64 + (orig >> 3);
  int qb = bid & 15, bh = bid >> 4;
  int q0 = qb * QBLK + wid * 32;
  const u16* Qb = Q + ((size_t)bh * SQ + q0) * HD;
  const u16* Kb = K + (size_t)bh * SQ * HD;
  const u16* Vb = Vt + (size_t)bh * HD * SQ;

  s16x8 qf[2][4];
#pragma unroll
  for (int mq = 0; mq < 2; mq++)
#pragma unroll
    for (int ks = 0; ks < 4; ks++)
      qf[mq][ks] = *(const s16x8*)(Qb + (size_t)(mq * 16 + l15) * HD + ks * 32 + lg * 8);

  // staging: 256 threads cover each 16 KB tile in 4 chunks of t*16
  int od[4], kro[4], kco[4], vro[4], vco[4];
#pragma unroll
  for (int p2 = 0; p2 < 4; p2++) {
    int off = t * 16 + p2 * 4096;
    od[p2] = off;
    kro[p2] = off >> 8; kco[p2] = (off & 255) ^ ((kro[p2] & 7) << 4);
    vro[p2] = off >> 7; vco[p2] = (off & 127) ^ ((vro[p2] & 7) << 4);
  }

  auto stage = [&](int buf, int kb) {
    const u16* Kt = Kb + (size_t)kb * KBLK * HD;
    const u16* Vs = Vb + kb * KBLK;
#pragma unroll
    for (int p2 = 0; p2 < 4; p2++)
      gld16(Kt + (size_t)kro[p2] * HD + (kco[p2] >> 1), &Ksh[buf][od[p2] >> 1]);
#pragma unroll
    for (int p2 = 0; p2 < 4; p2++)
      gld16(Vs + (size_t)vro[p2] * SQ + (vco[p2] >> 1), &Vsh[buf][od[p2] >> 1]);
  };

  f32x4 acc[2][8];
#pragma unroll
  for (int mq = 0; mq < 2; mq++)
#pragma unroll
    for (int i = 0; i < 8; i++) acc[mq][i] = (f32x4){0.f, 0.f, 0.f, 0.f};
  float m[2] = {-3.0e38f, -3.0e38f}, lsum[2] = {0.f, 0.f};

  stage(0, 0);
  __syncthreads();

#pragma unroll 1
  for (int kb = 0; kb < SQ / KBLK; kb++) {
    int cur = kb & 1;
    if (kb + 1 < SQ / KBLK) stage(cur ^ 1, kb + 1);
    // ---- S^T = K . Q^T : rows k (cb*16+lg*4+i), cols q (mq*16 + l15) ----
    f32x4 sa[2][4];
#pragma unroll
    for (int mq = 0; mq < 2; mq++)
#pragma unroll
      for (int cb = 0; cb < 4; cb++) sa[mq][cb] = (f32x4){0.f, 0.f, 0.f, 0.f};
    __builtin_amdgcn_s_setprio(1);
#pragma unroll
    for (int ks = 0; ks < 4; ks++) {
#pragma unroll
      for (int cb = 0; cb < 4; cb++) {
        int r = cb * 16 + l15;
        int off = r * 256 + ((ks * 64 + lg * 16) ^ ((r & 7) << 4));
        s16x8 kf = *(const s16x8*)((const char*)&Ksh[cur][0] + off);
        sa[0][cb] = MFMA16(kf, qf[0][ks], sa[0][cb], 0, 0, 0);
        sa[1][cb] = MFMA16(kf, qf[1][ks], sa[1][cb], 0, 0, 0);
      }
    }
    __builtin_amdgcn_s_setprio(0);
    // ---- row stats: lane l15 owns q-rows (mq*16 + l15) ----
    float rm[2];
#pragma unroll
    for (int mq = 0; mq < 2; mq++) {
      float r2 = sa[mq][0][0];
#pragma unroll
      for (int cb = 0; cb < 4; cb++)
#pragma unroll
        for (int i = 0; i < 4; i++) r2 = fmaxf(r2, sa[mq][cb][i]);
      r2 = fmaxf(r2, __shfl_xor(r2, 16));
      r2 = fmaxf(r2, __shfl_xor(r2, 32));
      rm[mq] = r2;
    }
    if (!__all(rm[0] <= m[0] + 8.0f && rm[1] <= m[1] + 8.0f)) {  // defer-max
#pragma unroll
      for (int mq = 0; mq < 2; mq++) {
        float mn = fmaxf(m[mq], rm[mq]);
        float al = __expf(m[mq] - mn);
        m[mq] = mn;
        float alq[4];
#pragma unroll
        for (int i = 0; i < 4; i++) alq[i] = __shfl(al, lg * 4 + i, 16);
#pragma unroll
        for (int c2 = 0; c2 < 8; c2++)
#pragma unroll
          for (int i = 0; i < 4; i++) acc[mq][c2][i] *= alq[i];
        lsum[mq] *= al;
      }
    }
#pragma unroll
    for (int mq = 0; mq < 2; mq++) {
      float ps = 0.f;
#pragma unroll
      for (int cb = 0; cb < 4; cb++)
#pragma unroll
        for (int i = 0; i < 4; i++) {
          sa[mq][cb][i] = __expf(sa[mq][cb][i] - m[mq]);
          ps += sa[mq][cb][i];
        }
      ps += __shfl_xor(ps, 16);
      ps += __shfl_xor(ps, 32);
      lsum[mq] += ps;
    }
    // ---- P -> per-wave LDS: row q = mq*16+l15, cols k; packed 8B, swizzled
#pragma unroll
    for (int mq = 0; mq < 2; mq++)
#pragma unroll
      for (int cb = 0; cb < 4; cb++) {
        u32 lo = (u32)f2bf(sa[mq][cb][0]) | ((u32)f2bf(sa[mq][cb][1]) << 16);
        u32 hi = (u32)f2bf(sa[mq][cb][2]) | ((u32)f2bf(sa[mq][cb][3]) << 16);
        int off = (mq * 16 + l15) * 128 + ((cb * 32 + lg * 8) ^ ((l15 & 7) << 4));
        *(uint2*)((char*)&Pl[wid][0] + off) = make_uint2(lo, hi);
      }
    s16x8 pf[2][2];
#pragma unroll
    for (int mq = 0; mq < 2; mq++)
#pragma unroll
      for (int k2 = 0; k2 < 2; k2++) {
        int off = (mq * 16 + l15) * 128 + ((k2 * 64 + lg * 16) ^ ((l15 & 7) << 4));
        pf[mq][k2] = *(const s16x8*)((const char*)&Pl[wid][0] + off);
      }
    // ---- PV: out 32 q-rows x 128 dh; each vf feeds both sub-blocks ----
    __builtin_amdgcn_s_setprio(1);
#pragma unroll
    for (int c2 = 0; c2 < 8; c2++) {
#pragma unroll
      for (int k2 = 0; k2 < 2; k2++) {
        int r = c2 * 16 + l15;
        int off = r * 128 + ((k2 * 64 + lg * 16) ^ ((r & 7) << 4));
        s16x8 vf = *(const s16x8*)((const char*)&Vsh[cur][0] + off);
        acc[0][c2] = MFMA16(pf[0][k2], vf, acc[0][c2], 0, 0, 0);
        acc[1][c2] = MFMA16(pf[1][k2], vf, acc[1][c2], 0, 0, 0);
      }
    }
    __builtin_amdgcn_s_setprio(0);
    __syncthreads();
  }
  int b = bh >> 4, h = bh & (NH - 1);
#pragma unroll
  for (int mq = 0; mq < 2; mq++) {
    float rin = 1.0f / lsum[mq];
    float rq[4];
#pragma unroll
    for (int i = 0; i < 4; i++) rq[i] = __shfl(rin, lg * 4 + i, 16);
#pragma unroll
    for (int c2 = 0; c2 < 8; c2++) {
#pragma unroll
      for (int i = 0; i < 4; i++) {
        int q = q0 + mq * 16 + lg * 4 + i;
        int dh = c2 * 16 + l15;
        Aout[((size_t)b * SQ + q) * DIMD + h * HD + dh] = f2bf(acc[mq][c2][i] * rq[i]);
      }
    }
  }
}

extern "C" void kernel_launch(void* const* d_in, const int* in_sizes, int n_in,
                              void* d_out, int out_size, void* d_ws, size_t ws_size,
                              hipStream_t stream) {
  (void)in_sizes; (void)n_in; (void)out_size; (void)ws_size;
  const float* x    = (const float*)d_in[0];
  const float* wq   = (const float*)d_in[1];
  const float* wk   = (const float*)d_in[2];
  const float* wv   = (const float*)d_in[3];
  const float* wo   = (const float*)d_in[4];
  const float* cosT = (const float*)d_in[5];
  const float* sinT = (const float*)d_in[6];
  float* out = (float*)d_out;

  char* p = (char*)d_ws;
  const size_t SZ_MD = (size_t)MR * DIMD * 2;    // 16.78 MB
  const size_t SZ_W  = (size_t)DIMD * DIMD * 2;  // 8.39 MB
  u16* xb   = (u16*)p; p += SZ_MD;
  u16* wqb  = (u16*)p; p += SZ_W;   // wq,wk,wv,wo contiguous (cvt_w4)
  u16* wkb  = (u16*)p; p += SZ_W;
  u16* wvb  = (u16*)p; p += SZ_W;
  u16* wob  = (u16*)p; p += SZ_W;
  u16* Qraw = (u16*)p; p += SZ_MD;
  u16* Kraw = (u16*)p; p += SZ_MD;
  u16* Qr   = (u16*)p; p += SZ_MD;
  u16* Kr   = (u16*)p; p += SZ_MD;
  u16* Vt   = (u16*)p; p += SZ_MD;
  u16* attnout = Qraw;  // Qraw dead after rope; reuse

  cvt_bf16<<<1024, 256, 0, stream>>>(x, xb, MR * DIMD / 4);
  cvt_w4<<<dim3(512, 4), 256, 0, stream>>>(wq, wk, wv, wo, wqb);

  gemm_bt<0><<<dim3(512, 3), 256, 0, stream>>>(xb, wqb, wkb, wvb, Qraw, Kraw, Vt, nullptr);
  rope_kernel<<<dim3(16384, 2), 256, 0, stream>>>(Qraw, Kraw, Qr, Kr, cosT, sinT);
  attn_kernel<<<512, 256, 0, stream>>>(Qr, Kr, Vt, attnout);
  gemm_bt<1><<<dim3(512, 1), 256, 0, stream>>>(attnout, wob, nullptr, nullptr,
                                               nullptr, nullptr, nullptr, out);
}